// Round 1
// baseline (704.343 us; speedup 1.0000x reference)
//
#include <hip/hip_runtime.h>
#include <hip/hip_bf16.h>

#define NN 50000
#define NE 800000
#define FD 128
#define L1CAP 16000
#define E1CAP 131072
#define E2CAP 32768
#define L2CAP 512

// ---------------- frontier construction ----------------

__global__ void k_mark(const int* __restrict__ states, const int* __restrict__ actions,
                       int* __restrict__ flagL2, int* __restrict__ flagL1,
                       int* __restrict__ nodeL2, int* __restrict__ cnt) {
    int i = blockIdx.x * blockDim.x + threadIdx.x;
    if (i == 0) cnt[3] = 257;   // fixed layer-2 slot count
    if (i < 257) {
        int n = (i < 256) ? states[i] : actions[0];
        flagL2[n] = i + 1;      // duplicate states race: one slot wins, fine (canonical)
        flagL1[n] = 1;
        nodeL2[i] = n;
    }
}

__global__ void k_scan_targets(const int* __restrict__ esrc, const int* __restrict__ edst,
                               const int* __restrict__ flagL2, int* __restrict__ flagL1,
                               float* __restrict__ deg2c, int* __restrict__ e2dst,
                               int* __restrict__ e2src, int* __restrict__ cnt) {
    int e = blockIdx.x * blockDim.x + threadIdx.x;
    if (e >= NE) return;
    int f = flagL2[edst[e]];
    if (f > 0) {
        int s = esrc[e];
        int i = atomicAdd(&cnt[2], 1);
        if (i < E2CAP) { e2dst[i] = f - 1; e2src[i] = s; }
        atomicAdd(&deg2c[f - 1], 1.0f);
        flagL1[s] = 1;          // idempotent mark
    }
}

__global__ void k_assign(int* __restrict__ flagL1, int* __restrict__ nodeL1,
                         int* __restrict__ cnt) {
    int n = blockIdx.x * blockDim.x + threadIdx.x;
    if (n >= NN) return;
    if (flagL1[n]) {
        int s = atomicAdd(&cnt[0], 1);
        if (s < L1CAP) { flagL1[n] = s + 1; nodeL1[s] = n; }
        else flagL1[n] = 0;     // overflow safety (never hit with this graph)
    }
}

__global__ void k_scan_l1(const int* __restrict__ esrc, const int* __restrict__ edst,
                          const int* __restrict__ flagL1, float* __restrict__ deg1c,
                          int* __restrict__ e1dst, int* __restrict__ e1src,
                          int* __restrict__ cnt) {
    int e = blockIdx.x * blockDim.x + threadIdx.x;
    if (e >= NE) return;
    int f = flagL1[edst[e]];
    if (f > 0) {
        int i = atomicAdd(&cnt[1], 1);
        if (i < E1CAP) { e1dst[i] = f - 1; e1src[i] = esrc[e]; }
        atomicAdd(&deg1c[f - 1], 1.0f);
    }
}

__global__ void k_selfrow2(const int* __restrict__ nodeL2, const int* __restrict__ flagL1,
                           int* __restrict__ selfRow2) {
    int s = threadIdx.x;
    if (s < 257) selfRow2[s] = flagL1[nodeL2[s]] - 1;
    else if (s < L2CAP) selfRow2[s] = 0;
}

// ---------------- aggregation scatter (1 wave per edge, float2/lane) ----------------

__global__ void k_scatter(const int* __restrict__ edst, const int* __restrict__ esrc,
                          const int* __restrict__ cntPtr, int cap,
                          const float* __restrict__ srcMat, const int* __restrict__ srcMap,
                          float* __restrict__ aggc) {
    int cnt = *cntPtr; if (cnt > cap) cnt = cap;
    int gtid = blockIdx.x * blockDim.x + threadIdx.x;
    int wid = gtid >> 6;
    int lane = threadIdx.x & 63;
    int nw = (gridDim.x * blockDim.x) >> 6;
    for (int e = wid; e < cnt; e += nw) {
        int d = edst[e], s = esrc[e];
        int row = srcMap ? (srcMap[s] - 1) : s;
        if (row < 0) continue;
        float2 v = ((const float2*)(srcMat + (size_t)row * FD))[lane];
        float* ap = aggc + (size_t)d * FD + lane * 2;
        atomicAdd(ap, v.x);
        atomicAdd(ap + 1, v.y);
    }
}

// ---------------- fused SAGE layer GEMM ----------------
// out[slot][o] = relu( self[slot]·Wself[o][:] + (agg[slot]/max(deg,1))·Wneigh[o][:] + b[o] )
// block = 128 thr, tile 32 slots x 128 outs, micro 4 slots x 8 outs.
// LDS row stride 132 -> sgroup broadcast reads hit banks {0,4,...,28}: conflict-free.

#define GSLOTS 32
#define LDSTR 132

__global__ __launch_bounds__(128) void k_gemm(
        const float* __restrict__ selfMat, const int* __restrict__ selfIdx,
        const float* __restrict__ aggc, const float* __restrict__ degc,
        const float* __restrict__ Wself, const float* __restrict__ Wneigh,
        const float* __restrict__ bias, float* __restrict__ outc,
        const int* __restrict__ cntPtr) {
    __shared__ float sx[GSLOTS][LDSTR];
    __shared__ float sa[GSLOTS][LDSTR];
    int cnt = *cntPtr;
    int base = blockIdx.x * GSLOTS;
    if (base >= cnt) return;
    int tid = threadIdx.x;

    for (int s = 0; s < GSLOTS; ++s) {
        int slot = base + s;
        int idx = (slot < cnt) ? selfIdx[slot] : 0;
        float inv = 1.0f / fmaxf(degc[slot], 1.0f);
        sx[s][tid] = selfMat[(size_t)idx * FD + tid];
        sa[s][tid] = aggc[(size_t)slot * FD + tid] * inv;
    }
    __syncthreads();

    int og = tid & 15;       // 16 out-groups -> o = og + 16*j
    int sg = tid >> 4;       // 8 slot-groups -> s = sg + 8*i
    float acc[4][8];
#pragma unroll
    for (int i = 0; i < 4; ++i)
#pragma unroll
        for (int j = 0; j < 8; ++j) acc[i][j] = 0.0f;

    for (int k = 0; k < FD; k += 4) {
        float4 xv[4], av[4];
#pragma unroll
        for (int i = 0; i < 4; ++i) {
            int s = sg + 8 * i;
            xv[i] = *(const float4*)&sx[s][k];
            av[i] = *(const float4*)&sa[s][k];
        }
#pragma unroll
        for (int j = 0; j < 8; ++j) {
            int o = og + 16 * j;
            float4 ws = *(const float4*)&Wself[(size_t)o * FD + k];
            float4 wn = *(const float4*)&Wneigh[(size_t)o * FD + k];
#pragma unroll
            for (int i = 0; i < 4; ++i) {
                acc[i][j] += xv[i].x * ws.x + xv[i].y * ws.y + xv[i].z * ws.z + xv[i].w * ws.w
                           + av[i].x * wn.x + av[i].y * wn.y + av[i].z * wn.z + av[i].w * wn.w;
            }
        }
    }

#pragma unroll
    for (int j = 0; j < 8; ++j) {
        int o = og + 16 * j;
        float b = bias[o];
#pragma unroll
        for (int i = 0; i < 4; ++i) {
            int slot = base + sg + 8 * i;
            outc[(size_t)slot * FD + o] = fmaxf(acc[i][j] + b, 0.0f);
        }
    }
}

// ---------------- readout ----------------

__global__ __launch_bounds__(256) void k_readout(
        const float* __restrict__ h2c, const int* __restrict__ flagL2,
        const int* __restrict__ states, const int* __restrict__ actions,
        const float* __restrict__ Wfc, const float* __restrict__ bfc,
        float* __restrict__ out) {
    __shared__ int smax[FD];       // float bits; valid max since h2 >= 0 (ReLU)
    __shared__ float red[256];
    int tid = threadIdx.x;
    if (tid < FD) smax[tid] = 0;   // bits of 0.0f
    __syncthreads();
    {
        int slot = flagL2[states[tid]] - 1;
        const float* row = h2c + (size_t)slot * FD;
#pragma unroll
        for (int f = 0; f < FD; f += 4) {
            float4 v = *(const float4*)(row + f);
            atomicMax(&smax[f],     __float_as_int(v.x));
            atomicMax(&smax[f + 1], __float_as_int(v.y));
            atomicMax(&smax[f + 2], __float_as_int(v.z));
            atomicMax(&smax[f + 3], __float_as_int(v.w));
        }
    }
    __syncthreads();
    float v = 0.0f;
    if (tid < FD) {
        int aslot = flagL2[actions[0]] - 1;
        float m = __int_as_float(smax[tid]);
        float av = h2c[(size_t)aslot * FD + tid];
        v = m * Wfc[tid] + av * Wfc[FD + tid];
    }
    red[tid] = v;
    __syncthreads();
    for (int s = 128; s > 0; s >>= 1) {
        if (tid < s) red[tid] += red[tid + s];
        __syncthreads();
    }
    if (tid == 0) out[0] = red[0] + bfc[0];
}

// ---------------- launch ----------------

extern "C" void kernel_launch(void* const* d_in, const int* in_sizes, int n_in,
                              void* d_out, int out_size, void* d_ws, size_t ws_size,
                              hipStream_t stream) {
    const float* x    = (const float*)d_in[0];
    const int* esrc   = (const int*)d_in[1];
    const int* edst   = (const int*)d_in[2];
    const int* states = (const int*)d_in[3];
    const int* acts   = (const int*)d_in[4];
    const float* W1s  = (const float*)d_in[5];
    const float* W1n  = (const float*)d_in[6];
    const float* b1   = (const float*)d_in[7];
    const float* W2s  = (const float*)d_in[8];
    const float* W2n  = (const float*)d_in[9];
    const float* b2   = (const float*)d_in[10];
    const float* Wfc  = (const float*)d_in[11];
    const float* bfc  = (const float*)d_in[12];
    float* out = (float*)d_out;

    char* ws = (char*)d_ws;
    size_t o = 0;
    // --- zeroed region (single contiguous memset) ---
    size_t off_cnt    = o; o += 256;
    size_t off_flagL2 = o; o += ((size_t)NN * 4 + 255) / 256 * 256;      // 200192
    size_t off_flagL1 = o; o += ((size_t)NN * 4 + 255) / 256 * 256;
    size_t off_deg1c  = o; o += ((size_t)L1CAP * 4 + 255) / 256 * 256;
    size_t off_deg2c  = o; o += (size_t)L2CAP * 4;
    size_t off_agg1c  = o; o += (size_t)L1CAP * FD * 4;                  // 8.192 MB
    size_t off_agg2c  = o; o += (size_t)L2CAP * FD * 4;
    size_t zero_bytes = o;
    // --- non-zeroed ---
    size_t off_nodeL2 = o; o += (size_t)L2CAP * 4;
    size_t off_selfR2 = o; o += (size_t)L2CAP * 4;
    size_t off_nodeL1 = o; o += ((size_t)L1CAP * 4 + 255) / 256 * 256;
    size_t off_e1dst  = o; o += (size_t)E1CAP * 4;
    size_t off_e1src  = o; o += (size_t)E1CAP * 4;
    size_t off_e2dst  = o; o += (size_t)E2CAP * 4;
    size_t off_e2src  = o; o += (size_t)E2CAP * 4;
    size_t off_h1c    = o; o += (size_t)L1CAP * FD * 4;
    size_t off_h2c    = o; o += (size_t)L2CAP * FD * 4;

    int*   cnt    = (int*)(ws + off_cnt);       // [0]=L1 slots [1]=E1 [2]=E2 [3]=L2 slots
    int*   flagL2 = (int*)(ws + off_flagL2);
    int*   flagL1 = (int*)(ws + off_flagL1);
    float* deg1c  = (float*)(ws + off_deg1c);
    float* deg2c  = (float*)(ws + off_deg2c);
    float* agg1c  = (float*)(ws + off_agg1c);
    float* agg2c  = (float*)(ws + off_agg2c);
    int*   nodeL2 = (int*)(ws + off_nodeL2);
    int*   selfR2 = (int*)(ws + off_selfR2);
    int*   nodeL1 = (int*)(ws + off_nodeL1);
    int*   e1dst  = (int*)(ws + off_e1dst);
    int*   e1src  = (int*)(ws + off_e1src);
    int*   e2dst  = (int*)(ws + off_e2dst);
    int*   e2src  = (int*)(ws + off_e2src);
    float* h1c    = (float*)(ws + off_h1c);
    float* h2c    = (float*)(ws + off_h2c);

    hipMemsetAsync(ws, 0, zero_bytes, stream);

    k_mark<<<1, 320, 0, stream>>>(states, acts, flagL2, flagL1, nodeL2, cnt);
    k_scan_targets<<<NE / 256, 256, 0, stream>>>(esrc, edst, flagL2, flagL1,
                                                 deg2c, e2dst, e2src, cnt);
    k_assign<<<(NN + 255) / 256, 256, 0, stream>>>(flagL1, nodeL1, cnt);
    k_scan_l1<<<NE / 256, 256, 0, stream>>>(esrc, edst, flagL1, deg1c, e1dst, e1src, cnt);
    k_selfrow2<<<1, 512, 0, stream>>>(nodeL2, flagL1, selfR2);

    // layer 1: aggregate x over E1, then fused GEMM -> h1c (compact L1 slots)
    k_scatter<<<512, 256, 0, stream>>>(e1dst, e1src, cnt + 1, E1CAP, x, nullptr, agg1c);
    k_gemm<<<L1CAP / GSLOTS, 128, 0, stream>>>(x, nodeL1, agg1c, deg1c, W1s, W1n, b1,
                                               h1c, cnt + 0);
    // layer 2: aggregate h1 over E2, fused GEMM -> h2c (257 slots)
    k_scatter<<<128, 256, 0, stream>>>(e2dst, e2src, cnt + 2, E2CAP, h1c, flagL1, agg2c);
    k_gemm<<<L2CAP / GSLOTS, 128, 0, stream>>>(h1c, selfR2, agg2c, deg2c, W2s, W2n, b2,
                                               h2c, cnt + 3);

    k_readout<<<1, 256, 0, stream>>>(h2c, flagL2, states, acts, Wfc, bfc, out);
}

// Round 2
// 472.778 us; speedup vs baseline: 1.4898x; 1.4898x over previous
//
#include <hip/hip_runtime.h>
#include <hip/hip_bf16.h>

#define NN 50000
#define NE 800000
#define FD 128
#define L1CAP 16000
#define E1CAP 131072
#define E2CAP 32768
#define L2CAP 512

// ---------------- frontier construction ----------------

__global__ void k_mark(const int* __restrict__ states, const int* __restrict__ actions,
                       int* __restrict__ flagL2, int* __restrict__ flagL1,
                       int* __restrict__ nodeL2, int* __restrict__ cnt) {
    int i = blockIdx.x * blockDim.x + threadIdx.x;
    if (i == 0) cnt[3] = 257;   // fixed layer-2 slot count
    if (i < 257) {
        int n = (i < 256) ? states[i] : actions[0];
        flagL2[n] = i + 1;      // duplicate states race: one slot wins, fine (canonical)
        flagL1[n] = 1;
        nodeL2[i] = n;
    }
}

__global__ void k_scan_targets(const int* __restrict__ esrc, const int* __restrict__ edst,
                               const int* __restrict__ flagL2, int* __restrict__ flagL1,
                               float* __restrict__ deg2c, int* __restrict__ e2dst,
                               int* __restrict__ e2src, int* __restrict__ cnt) {
    int e = blockIdx.x * blockDim.x + threadIdx.x;
    if (e >= NE) return;
    int f = flagL2[edst[e]];
    if (f > 0) {
        int s = esrc[e];
        int i = atomicAdd(&cnt[2], 1);
        if (i < E2CAP) { e2dst[i] = f - 1; e2src[i] = s; }
        atomicAdd(&deg2c[f - 1], 1.0f);
        flagL1[s] = 1;          // idempotent mark
    }
}

__global__ void k_assign(int* __restrict__ flagL1, int* __restrict__ nodeL1,
                         int* __restrict__ cnt) {
    int n = blockIdx.x * blockDim.x + threadIdx.x;
    if (n >= NN) return;
    if (flagL1[n]) {
        int s = atomicAdd(&cnt[0], 1);
        if (s < L1CAP) { flagL1[n] = s + 1; nodeL1[s] = n; }
        else flagL1[n] = 0;     // overflow safety (never hit with this graph)
    }
}

__global__ void k_scan_l1(const int* __restrict__ esrc, const int* __restrict__ edst,
                          const int* __restrict__ flagL1, float* __restrict__ deg1c,
                          int* __restrict__ e1dst, int* __restrict__ e1src,
                          int* __restrict__ cnt) {
    int e = blockIdx.x * blockDim.x + threadIdx.x;
    if (e >= NE) return;
    int f = flagL1[edst[e]];
    if (f > 0) {
        int i = atomicAdd(&cnt[1], 1);
        if (i < E1CAP) { e1dst[i] = f - 1; e1src[i] = esrc[e]; }
        atomicAdd(&deg1c[f - 1], 1.0f);
    }
}

__global__ void k_selfrow2(const int* __restrict__ nodeL2, const int* __restrict__ flagL1,
                           int* __restrict__ selfRow2) {
    int s = threadIdx.x;
    if (s < 257) selfRow2[s] = flagL1[nodeL2[s]] - 1;
    else if (s < L2CAP) selfRow2[s] = 0;
}

// ---------------- aggregation scatter (1 wave per edge, float2/lane) ----------------

__global__ void k_scatter(const int* __restrict__ edst, const int* __restrict__ esrc,
                          const int* __restrict__ cntPtr, int cap,
                          const float* __restrict__ srcMat, const int* __restrict__ srcMap,
                          float* __restrict__ aggc) {
    int cnt = *cntPtr; if (cnt > cap) cnt = cap;
    int gtid = blockIdx.x * blockDim.x + threadIdx.x;
    int wid = gtid >> 6;
    int lane = threadIdx.x & 63;
    int nw = (gridDim.x * blockDim.x) >> 6;
    for (int e = wid; e < cnt; e += nw) {
        int d = edst[e], s = esrc[e];
        int row = srcMap ? (srcMap[s] - 1) : s;
        if (row < 0) continue;
        float2 v = ((const float2*)(srcMat + (size_t)row * FD))[lane];
        float* ap = aggc + (size_t)d * FD + lane * 2;
        atomicAdd(ap, v.x);
        atomicAdd(ap + 1, v.y);
    }
}

// ---------------- fused SAGE layer GEMM ----------------
// out[slot][o] = relu( self[slot]·Wself[o][:] + (agg[slot]/max(deg,1))·Wneigh[o][:] + b[o] )
// block = 128 thr, tile 32 slots x 128 outs, micro 4 slots x 8 outs.
// LDS row stride 132 -> sgroup broadcast reads hit banks {0,4,...,28}: conflict-free.

#define GSLOTS 32
#define LDSTR 132

__global__ __launch_bounds__(128) void k_gemm(
        const float* __restrict__ selfMat, const int* __restrict__ selfIdx,
        const float* __restrict__ aggc, const float* __restrict__ degc,
        const float* __restrict__ Wself, const float* __restrict__ Wneigh,
        const float* __restrict__ bias, float* __restrict__ outc,
        const int* __restrict__ cntPtr) {
    __shared__ float sx[GSLOTS][LDSTR];
    __shared__ float sa[GSLOTS][LDSTR];
    int cnt = *cntPtr;
    int base = blockIdx.x * GSLOTS;
    if (base >= cnt) return;
    int tid = threadIdx.x;

    for (int s = 0; s < GSLOTS; ++s) {
        int slot = base + s;
        int idx = (slot < cnt) ? selfIdx[slot] : 0;
        float inv = 1.0f / fmaxf(degc[slot], 1.0f);
        sx[s][tid] = selfMat[(size_t)idx * FD + tid];
        sa[s][tid] = aggc[(size_t)slot * FD + tid] * inv;
    }
    __syncthreads();

    int og = tid & 15;       // 16 out-groups -> o = og + 16*j
    int sg = tid >> 4;       // 8 slot-groups -> s = sg + 8*i
    float acc[4][8];
#pragma unroll
    for (int i = 0; i < 4; ++i)
#pragma unroll
        for (int j = 0; j < 8; ++j) acc[i][j] = 0.0f;

    for (int k = 0; k < FD; k += 4) {
        float4 xv[4], av[4];
#pragma unroll
        for (int i = 0; i < 4; ++i) {
            int s = sg + 8 * i;
            xv[i] = *(const float4*)&sx[s][k];
            av[i] = *(const float4*)&sa[s][k];
        }
#pragma unroll
        for (int j = 0; j < 8; ++j) {
            int o = og + 16 * j;
            float4 ws = *(const float4*)&Wself[(size_t)o * FD + k];
            float4 wn = *(const float4*)&Wneigh[(size_t)o * FD + k];
#pragma unroll
            for (int i = 0; i < 4; ++i) {
                acc[i][j] += xv[i].x * ws.x + xv[i].y * ws.y + xv[i].z * ws.z + xv[i].w * ws.w
                           + av[i].x * wn.x + av[i].y * wn.y + av[i].z * wn.z + av[i].w * wn.w;
            }
        }
    }

#pragma unroll
    for (int j = 0; j < 8; ++j) {
        int o = og + 16 * j;
        float b = bias[o];
#pragma unroll
        for (int i = 0; i < 4; ++i) {
            int slot = base + sg + 8 * i;
            outc[(size_t)slot * FD + o] = fmaxf(acc[i][j] + b, 0.0f);
        }
    }
}

// ---------------- readout ----------------
// Transposed: thread owns one feature, loops over state rows with a register
// fmax chain. Zero atomics (previous version: 32768 contended LDS atomics
// = 258 us). Two thread-halves each cover 128 states, merged via LDS.

__global__ __launch_bounds__(256) void k_readout(
        const float* __restrict__ h2c, const int* __restrict__ flagL2,
        const int* __restrict__ states, const int* __restrict__ actions,
        const float* __restrict__ Wfc, const float* __restrict__ bfc,
        float* __restrict__ out) {
    __shared__ int slotS[256];
    __shared__ float halfmax[2][FD];
    __shared__ float red[256];
    int tid = threadIdx.x;
    slotS[tid] = flagL2[states[tid]] - 1;
    __syncthreads();

    int f = tid & (FD - 1);
    int half = tid >> 7;             // 0 or 1
    float m = 0.0f;                  // h2 >= 0 post-ReLU, 0 is identity for max
#pragma unroll 8
    for (int s = half * 128; s < half * 128 + 128; ++s) {
        m = fmaxf(m, h2c[(size_t)slotS[s] * FD + f]);
    }
    halfmax[half][f] = m;
    __syncthreads();

    float v = 0.0f;
    if (tid < FD) {
        int aslot = flagL2[actions[0]] - 1;
        float mm = fmaxf(halfmax[0][tid], halfmax[1][tid]);
        float av = h2c[(size_t)aslot * FD + tid];
        v = mm * Wfc[tid] + av * Wfc[FD + tid];
    }
    red[tid] = v;
    __syncthreads();
    for (int s = 128; s > 0; s >>= 1) {
        if (tid < s) red[tid] += red[tid + s];
        __syncthreads();
    }
    if (tid == 0) out[0] = red[0] + bfc[0];
}

// ---------------- launch ----------------

extern "C" void kernel_launch(void* const* d_in, const int* in_sizes, int n_in,
                              void* d_out, int out_size, void* d_ws, size_t ws_size,
                              hipStream_t stream) {
    const float* x    = (const float*)d_in[0];
    const int* esrc   = (const int*)d_in[1];
    const int* edst   = (const int*)d_in[2];
    const int* states = (const int*)d_in[3];
    const int* acts   = (const int*)d_in[4];
    const float* W1s  = (const float*)d_in[5];
    const float* W1n  = (const float*)d_in[6];
    const float* b1   = (const float*)d_in[7];
    const float* W2s  = (const float*)d_in[8];
    const float* W2n  = (const float*)d_in[9];
    const float* b2   = (const float*)d_in[10];
    const float* Wfc  = (const float*)d_in[11];
    const float* bfc  = (const float*)d_in[12];
    float* out = (float*)d_out;

    char* ws = (char*)d_ws;
    size_t o = 0;
    // --- zeroed region (single contiguous memset) ---
    size_t off_cnt    = o; o += 256;
    size_t off_flagL2 = o; o += ((size_t)NN * 4 + 255) / 256 * 256;      // 200192
    size_t off_flagL1 = o; o += ((size_t)NN * 4 + 255) / 256 * 256;
    size_t off_deg1c  = o; o += ((size_t)L1CAP * 4 + 255) / 256 * 256;
    size_t off_deg2c  = o; o += (size_t)L2CAP * 4;
    size_t off_agg1c  = o; o += (size_t)L1CAP * FD * 4;                  // 8.192 MB
    size_t off_agg2c  = o; o += (size_t)L2CAP * FD * 4;
    size_t zero_bytes = o;
    // --- non-zeroed ---
    size_t off_nodeL2 = o; o += (size_t)L2CAP * 4;
    size_t off_selfR2 = o; o += (size_t)L2CAP * 4;
    size_t off_nodeL1 = o; o += ((size_t)L1CAP * 4 + 255) / 256 * 256;
    size_t off_e1dst  = o; o += (size_t)E1CAP * 4;
    size_t off_e1src  = o; o += (size_t)E1CAP * 4;
    size_t off_e2dst  = o; o += (size_t)E2CAP * 4;
    size_t off_e2src  = o; o += (size_t)E2CAP * 4;
    size_t off_h1c    = o; o += (size_t)L1CAP * FD * 4;
    size_t off_h2c    = o; o += (size_t)L2CAP * FD * 4;

    int*   cnt    = (int*)(ws + off_cnt);       // [0]=L1 slots [1]=E1 [2]=E2 [3]=L2 slots
    int*   flagL2 = (int*)(ws + off_flagL2);
    int*   flagL1 = (int*)(ws + off_flagL1);
    float* deg1c  = (float*)(ws + off_deg1c);
    float* deg2c  = (float*)(ws + off_deg2c);
    float* agg1c  = (float*)(ws + off_agg1c);
    float* agg2c  = (float*)(ws + off_agg2c);
    int*   nodeL2 = (int*)(ws + off_nodeL2);
    int*   selfR2 = (int*)(ws + off_selfR2);
    int*   nodeL1 = (int*)(ws + off_nodeL1);
    int*   e1dst  = (int*)(ws + off_e1dst);
    int*   e1src  = (int*)(ws + off_e1src);
    int*   e2dst  = (int*)(ws + off_e2dst);
    int*   e2src  = (int*)(ws + off_e2src);
    float* h1c    = (float*)(ws + off_h1c);
    float* h2c    = (float*)(ws + off_h2c);

    hipMemsetAsync(ws, 0, zero_bytes, stream);

    k_mark<<<1, 320, 0, stream>>>(states, acts, flagL2, flagL1, nodeL2, cnt);
    k_scan_targets<<<NE / 256, 256, 0, stream>>>(esrc, edst, flagL2, flagL1,
                                                 deg2c, e2dst, e2src, cnt);
    k_assign<<<(NN + 255) / 256, 256, 0, stream>>>(flagL1, nodeL1, cnt);
    k_scan_l1<<<NE / 256, 256, 0, stream>>>(esrc, edst, flagL1, deg1c, e1dst, e1src, cnt);
    k_selfrow2<<<1, 512, 0, stream>>>(nodeL2, flagL1, selfR2);

    // layer 1: aggregate x over E1, then fused GEMM -> h1c (compact L1 slots)
    k_scatter<<<512, 256, 0, stream>>>(e1dst, e1src, cnt + 1, E1CAP, x, nullptr, agg1c);
    k_gemm<<<L1CAP / GSLOTS, 128, 0, stream>>>(x, nodeL1, agg1c, deg1c, W1s, W1n, b1,
                                               h1c, cnt + 0);
    // layer 2: aggregate h1 over E2, fused GEMM -> h2c (257 slots)
    k_scatter<<<128, 256, 0, stream>>>(e2dst, e2src, cnt + 2, E2CAP, h1c, flagL1, agg2c);
    k_gemm<<<L2CAP / GSLOTS, 128, 0, stream>>>(h1c, selfR2, agg2c, deg2c, W2s, W2n, b2,
                                               h2c, cnt + 3);

    k_readout<<<1, 256, 0, stream>>>(h2c, flagL2, states, acts, Wfc, bfc, out);
}

// Round 3
// 356.739 us; speedup vs baseline: 1.9744x; 1.3253x over previous
//
#include <hip/hip_runtime.h>
#include <hip/hip_bf16.h>

#define NN 50000
#define NE 800000
#define FD 128
#define L1CAP 16000
#define E1CAP 131072
#define E2CAP 32768
#define L2CAP 512

// ---------------- frontier construction ----------------

__global__ void k_mark(const int* __restrict__ states, const int* __restrict__ actions,
                       int* __restrict__ flagL2, int* __restrict__ flagL1,
                       int* __restrict__ nodeL2, int* __restrict__ cnt) {
    int i = blockIdx.x * blockDim.x + threadIdx.x;
    if (i == 0) cnt[3] = 257;   // fixed layer-2 slot count
    if (i < 257) {
        int n = (i < 256) ? states[i] : actions[0];
        flagL2[n] = i + 1;      // duplicate states race: one slot wins, fine (canonical)
        flagL1[n] = 1;
        nodeL2[i] = n;
    }
}

// Edge scan, 4 edges/thread, wave-aggregated compaction counter.
// Previous version: one same-address global atomic PER HIT (70K x ~5cyc
// serialized = 146 us). Now: 6-shfl wave scan + ONE atomic per wave.

__global__ __launch_bounds__(256) void k_scan_targets(
        const int4* __restrict__ esrc4, const int4* __restrict__ edst4,
        const int* __restrict__ flagL2, int* __restrict__ flagL1,
        float* __restrict__ deg2c, int* __restrict__ e2dst,
        int* __restrict__ e2src, int* __restrict__ cnt) {
    int t = blockIdx.x * blockDim.x + threadIdx.x;
    int lane = threadIdx.x & 63;
    int f[4] = {0, 0, 0, 0};
    int s[4];
    if (t < NE / 4) {
        int4 d4 = edst4[t];
        int4 s4 = esrc4[t];
        f[0] = flagL2[d4.x]; f[1] = flagL2[d4.y];
        f[2] = flagL2[d4.z]; f[3] = flagL2[d4.w];
        s[0] = s4.x; s[1] = s4.y; s[2] = s4.z; s[3] = s4.w;
    }
    int c = (f[0] > 0) + (f[1] > 0) + (f[2] > 0) + (f[3] > 0);
    int scan = c;
#pragma unroll
    for (int off = 1; off < 64; off <<= 1) {
        int n = __shfl_up(scan, off, 64);
        if (lane >= off) scan += n;
    }
    int total = __shfl(scan, 63, 64);
    int base = 0;
    if (lane == 63 && total) base = atomicAdd(&cnt[2], total);
    base = __shfl(base, 63, 64);
    int idx = base + scan - c;
#pragma unroll
    for (int j = 0; j < 4; ++j) {
        if (f[j] > 0) {
            if (idx < E2CAP) { e2dst[idx] = f[j] - 1; e2src[idx] = s[j]; }
            atomicAdd(&deg2c[f[j] - 1], 1.0f);
            flagL1[s[j]] = 1;       // idempotent mark
            ++idx;
        }
    }
}

__global__ __launch_bounds__(256) void k_assign(
        int* __restrict__ flagL1, int* __restrict__ nodeL1, int* __restrict__ cnt) {
    int n = blockIdx.x * blockDim.x + threadIdx.x;
    bool pred = (n < NN) && (flagL1[n] != 0);
    unsigned long long mask = __ballot(pred);
    if (mask == 0) return;
    int lane = threadIdx.x & 63;
    int prefix = __popcll(mask & ((1ull << lane) - 1));
    int fl = __ffsll((long long)mask) - 1;
    int base = 0;
    if (lane == fl) base = atomicAdd(&cnt[0], __popcll(mask));
    base = __shfl(base, fl, 64);
    if (pred) {
        int slot = base + prefix;
        if (slot < L1CAP) { flagL1[n] = slot + 1; nodeL1[slot] = n; }
        else flagL1[n] = 0;     // overflow safety (never hit with this graph)
    }
}

__global__ __launch_bounds__(256) void k_scan_l1(
        const int4* __restrict__ esrc4, const int4* __restrict__ edst4,
        const int* __restrict__ flagL1, float* __restrict__ deg1c,
        int* __restrict__ e1dst, int* __restrict__ e1src, int* __restrict__ cnt) {
    int t = blockIdx.x * blockDim.x + threadIdx.x;
    int lane = threadIdx.x & 63;
    int f[4] = {0, 0, 0, 0};
    int s[4];
    if (t < NE / 4) {
        int4 d4 = edst4[t];
        int4 s4 = esrc4[t];
        f[0] = flagL1[d4.x]; f[1] = flagL1[d4.y];
        f[2] = flagL1[d4.z]; f[3] = flagL1[d4.w];
        s[0] = s4.x; s[1] = s4.y; s[2] = s4.z; s[3] = s4.w;
    }
    int c = (f[0] > 0) + (f[1] > 0) + (f[2] > 0) + (f[3] > 0);
    int scan = c;
#pragma unroll
    for (int off = 1; off < 64; off <<= 1) {
        int n = __shfl_up(scan, off, 64);
        if (lane >= off) scan += n;
    }
    int total = __shfl(scan, 63, 64);
    int base = 0;
    if (lane == 63 && total) base = atomicAdd(&cnt[1], total);
    base = __shfl(base, 63, 64);
    int idx = base + scan - c;
#pragma unroll
    for (int j = 0; j < 4; ++j) {
        if (f[j] > 0) {
            if (idx < E1CAP) { e1dst[idx] = f[j] - 1; e1src[idx] = s[j]; }
            atomicAdd(&deg1c[f[j] - 1], 1.0f);
            ++idx;
        }
    }
}

__global__ void k_selfrow2(const int* __restrict__ nodeL2, const int* __restrict__ flagL1,
                           int* __restrict__ selfRow2) {
    int s = threadIdx.x;
    if (s < 257) selfRow2[s] = flagL1[nodeL2[s]] - 1;
    else if (s < L2CAP) selfRow2[s] = 0;
}

// ---------------- aggregation scatter (1 wave per edge, float2/lane) ----------------

__global__ void k_scatter(const int* __restrict__ edst, const int* __restrict__ esrc,
                          const int* __restrict__ cntPtr, int cap,
                          const float* __restrict__ srcMat, const int* __restrict__ srcMap,
                          float* __restrict__ aggc) {
    int cnt = *cntPtr; if (cnt > cap) cnt = cap;
    int gtid = blockIdx.x * blockDim.x + threadIdx.x;
    int wid = gtid >> 6;
    int lane = threadIdx.x & 63;
    int nw = (gridDim.x * blockDim.x) >> 6;
    for (int e = wid; e < cnt; e += nw) {
        int d = edst[e], s = esrc[e];
        int row = srcMap ? (srcMap[s] - 1) : s;
        if (row < 0) continue;
        float2 v = ((const float2*)(srcMat + (size_t)row * FD))[lane];
        float* ap = aggc + (size_t)d * FD + lane * 2;
        atomicAdd(ap, v.x);
        atomicAdd(ap + 1, v.y);
    }
}

// ---------------- fused SAGE layer GEMM ----------------
// out[slot][o] = relu( self[slot]·Wself[o][:] + (agg[slot]/max(deg,1))·Wneigh[o][:] + b[o] )
// block = 128 thr, tile 32 slots x 128 outs, micro 4 slots x 8 outs.
// LDS row stride 132 -> sgroup broadcast reads hit banks {0,4,...,28}: conflict-free.

#define GSLOTS 32
#define LDSTR 132

__global__ __launch_bounds__(128) void k_gemm(
        const float* __restrict__ selfMat, const int* __restrict__ selfIdx,
        const float* __restrict__ aggc, const float* __restrict__ degc,
        const float* __restrict__ Wself, const float* __restrict__ Wneigh,
        const float* __restrict__ bias, float* __restrict__ outc,
        const int* __restrict__ cntPtr) {
    __shared__ float sx[GSLOTS][LDSTR];
    __shared__ float sa[GSLOTS][LDSTR];
    int cnt = *cntPtr;
    int base = blockIdx.x * GSLOTS;
    if (base >= cnt) return;
    int tid = threadIdx.x;

    for (int s = 0; s < GSLOTS; ++s) {
        int slot = base + s;
        int idx = (slot < cnt) ? selfIdx[slot] : 0;
        float inv = 1.0f / fmaxf(degc[slot], 1.0f);
        sx[s][tid] = selfMat[(size_t)idx * FD + tid];
        sa[s][tid] = aggc[(size_t)slot * FD + tid] * inv;
    }
    __syncthreads();

    int og = tid & 15;       // 16 out-groups -> o = og + 16*j
    int sg = tid >> 4;       // 8 slot-groups -> s = sg + 8*i
    float acc[4][8];
#pragma unroll
    for (int i = 0; i < 4; ++i)
#pragma unroll
        for (int j = 0; j < 8; ++j) acc[i][j] = 0.0f;

    for (int k = 0; k < FD; k += 4) {
        float4 xv[4], av[4];
#pragma unroll
        for (int i = 0; i < 4; ++i) {
            int s = sg + 8 * i;
            xv[i] = *(const float4*)&sx[s][k];
            av[i] = *(const float4*)&sa[s][k];
        }
#pragma unroll
        for (int j = 0; j < 8; ++j) {
            int o = og + 16 * j;
            float4 ws = *(const float4*)&Wself[(size_t)o * FD + k];
            float4 wn = *(const float4*)&Wneigh[(size_t)o * FD + k];
#pragma unroll
            for (int i = 0; i < 4; ++i) {
                acc[i][j] += xv[i].x * ws.x + xv[i].y * ws.y + xv[i].z * ws.z + xv[i].w * ws.w
                           + av[i].x * wn.x + av[i].y * wn.y + av[i].z * wn.z + av[i].w * wn.w;
            }
        }
    }

#pragma unroll
    for (int j = 0; j < 8; ++j) {
        int o = og + 16 * j;
        float b = bias[o];
#pragma unroll
        for (int i = 0; i < 4; ++i) {
            int slot = base + sg + 8 * i;
            outc[(size_t)slot * FD + o] = fmaxf(acc[i][j] + b, 0.0f);
        }
    }
}

// ---------------- readout ----------------
// Transposed: thread owns one feature, loops over state rows with a register
// fmax chain. Zero atomics. Two thread-halves each cover 128 states.

__global__ __launch_bounds__(256) void k_readout(
        const float* __restrict__ h2c, const int* __restrict__ flagL2,
        const int* __restrict__ states, const int* __restrict__ actions,
        const float* __restrict__ Wfc, const float* __restrict__ bfc,
        float* __restrict__ out) {
    __shared__ int slotS[256];
    __shared__ float halfmax[2][FD];
    __shared__ float red[256];
    int tid = threadIdx.x;
    slotS[tid] = flagL2[states[tid]] - 1;
    __syncthreads();

    int f = tid & (FD - 1);
    int half = tid >> 7;             // 0 or 1
    float m = 0.0f;                  // h2 >= 0 post-ReLU, 0 is identity for max
#pragma unroll 8
    for (int s = half * 128; s < half * 128 + 128; ++s) {
        m = fmaxf(m, h2c[(size_t)slotS[s] * FD + f]);
    }
    halfmax[half][f] = m;
    __syncthreads();

    float v = 0.0f;
    if (tid < FD) {
        int aslot = flagL2[actions[0]] - 1;
        float mm = fmaxf(halfmax[0][tid], halfmax[1][tid]);
        float av = h2c[(size_t)aslot * FD + tid];
        v = mm * Wfc[tid] + av * Wfc[FD + tid];
    }
    red[tid] = v;
    __syncthreads();
    for (int s = 128; s > 0; s >>= 1) {
        if (tid < s) red[tid] += red[tid + s];
        __syncthreads();
    }
    if (tid == 0) out[0] = red[0] + bfc[0];
}

// ---------------- launch ----------------

extern "C" void kernel_launch(void* const* d_in, const int* in_sizes, int n_in,
                              void* d_out, int out_size, void* d_ws, size_t ws_size,
                              hipStream_t stream) {
    const float* x    = (const float*)d_in[0];
    const int* esrc   = (const int*)d_in[1];
    const int* edst   = (const int*)d_in[2];
    const int* states = (const int*)d_in[3];
    const int* acts   = (const int*)d_in[4];
    const float* W1s  = (const float*)d_in[5];
    const float* W1n  = (const float*)d_in[6];
    const float* b1   = (const float*)d_in[7];
    const float* W2s  = (const float*)d_in[8];
    const float* W2n  = (const float*)d_in[9];
    const float* b2   = (const float*)d_in[10];
    const float* Wfc  = (const float*)d_in[11];
    const float* bfc  = (const float*)d_in[12];
    float* out = (float*)d_out;

    char* ws = (char*)d_ws;
    size_t o = 0;
    // --- zeroed region (single contiguous memset) ---
    size_t off_cnt    = o; o += 256;
    size_t off_flagL2 = o; o += ((size_t)NN * 4 + 255) / 256 * 256;      // 200192
    size_t off_flagL1 = o; o += ((size_t)NN * 4 + 255) / 256 * 256;
    size_t off_deg1c  = o; o += ((size_t)L1CAP * 4 + 255) / 256 * 256;
    size_t off_deg2c  = o; o += (size_t)L2CAP * 4;
    size_t off_agg1c  = o; o += (size_t)L1CAP * FD * 4;                  // 8.192 MB
    size_t off_agg2c  = o; o += (size_t)L2CAP * FD * 4;
    size_t zero_bytes = o;
    // --- non-zeroed ---
    size_t off_nodeL2 = o; o += (size_t)L2CAP * 4;
    size_t off_selfR2 = o; o += (size_t)L2CAP * 4;
    size_t off_nodeL1 = o; o += ((size_t)L1CAP * 4 + 255) / 256 * 256;
    size_t off_e1dst  = o; o += (size_t)E1CAP * 4;
    size_t off_e1src  = o; o += (size_t)E1CAP * 4;
    size_t off_e2dst  = o; o += (size_t)E2CAP * 4;
    size_t off_e2src  = o; o += (size_t)E2CAP * 4;
    size_t off_h1c    = o; o += (size_t)L1CAP * FD * 4;
    size_t off_h2c    = o; o += (size_t)L2CAP * FD * 4;

    int*   cnt    = (int*)(ws + off_cnt);       // [0]=L1 slots [1]=E1 [2]=E2 [3]=L2 slots
    int*   flagL2 = (int*)(ws + off_flagL2);
    int*   flagL1 = (int*)(ws + off_flagL1);
    float* deg1c  = (float*)(ws + off_deg1c);
    float* deg2c  = (float*)(ws + off_deg2c);
    float* agg1c  = (float*)(ws + off_agg1c);
    float* agg2c  = (float*)(ws + off_agg2c);
    int*   nodeL2 = (int*)(ws + off_nodeL2);
    int*   selfR2 = (int*)(ws + off_selfR2);
    int*   nodeL1 = (int*)(ws + off_nodeL1);
    int*   e1dst  = (int*)(ws + off_e1dst);
    int*   e1src  = (int*)(ws + off_e1src);
    int*   e2dst  = (int*)(ws + off_e2dst);
    int*   e2src  = (int*)(ws + off_e2src);
    float* h1c    = (float*)(ws + off_h1c);
    float* h2c    = (float*)(ws + off_h2c);

    hipMemsetAsync(ws, 0, zero_bytes, stream);

    k_mark<<<1, 320, 0, stream>>>(states, acts, flagL2, flagL1, nodeL2, cnt);
    k_scan_targets<<<(NE / 4 + 255) / 256, 256, 0, stream>>>(
        (const int4*)esrc, (const int4*)edst, flagL2, flagL1, deg2c, e2dst, e2src, cnt);
    k_assign<<<(NN + 255) / 256, 256, 0, stream>>>(flagL1, nodeL1, cnt);
    k_scan_l1<<<(NE / 4 + 255) / 256, 256, 0, stream>>>(
        (const int4*)esrc, (const int4*)edst, flagL1, deg1c, e1dst, e1src, cnt);
    k_selfrow2<<<1, 512, 0, stream>>>(nodeL2, flagL1, selfR2);

    // layer 1: aggregate x over E1, then fused GEMM -> h1c (compact L1 slots)
    k_scatter<<<512, 256, 0, stream>>>(e1dst, e1src, cnt + 1, E1CAP, x, nullptr, agg1c);
    k_gemm<<<L1CAP / GSLOTS, 128, 0, stream>>>(x, nodeL1, agg1c, deg1c, W1s, W1n, b1,
                                               h1c, cnt + 0);
    // layer 2: aggregate h1 over E2, fused GEMM -> h2c (257 slots)
    k_scatter<<<128, 256, 0, stream>>>(e2dst, e2src, cnt + 2, E2CAP, h1c, flagL1, agg2c);
    k_gemm<<<L2CAP / GSLOTS, 128, 0, stream>>>(h1c, selfR2, agg2c, deg2c, W2s, W2n, b2,
                                               h2c, cnt + 3);

    k_readout<<<1, 256, 0, stream>>>(h2c, flagL2, states, acts, Wfc, bfc, out);
}